// Round 4
// baseline (13532.870 us; speedup 1.0000x reference)
//
#include <hip/hip_runtime.h>

#define NN 50000
#define HID 128
#define IN_C 100
#define OUT_C 40

// ---------------------------------------------------------------------------
__global__ __launch_bounds__(256)
void hist_kernel(const int* __restrict__ dst, int* __restrict__ deg, int E) {
    int e = blockIdx.x * 256 + threadIdx.x;
    if (e < E) atomicAdd(&deg[dst[e]], 1);
}

// ---------------------------------------------------------------------------
__global__ __launch_bounds__(1024)
void scan_kernel(const int* __restrict__ deg, int* __restrict__ row_start,
                 int* __restrict__ cursor, int N) {
    __shared__ int s[1024];
    const int t = threadIdx.x;
    int running = 0;
    for (int c0 = 0; c0 < N; c0 += 1024) {
        int i = c0 + t;
        int v = (i < N) ? deg[i] : 0;
        s[t] = v;
        __syncthreads();
        for (int off = 1; off < 1024; off <<= 1) {
            int x = (t >= off) ? s[t - off] : 0;
            __syncthreads();
            s[t] += x;
            __syncthreads();
        }
        if (i < N) {
            int ex = running + s[t] - v;
            row_start[i] = ex;
            cursor[i] = ex;
        }
        running += s[1023];
        __syncthreads();
    }
    if (t == 0) row_start[N] = running;
}

// ---------------------------------------------------------------------------
__global__ __launch_bounds__(256)
void scatter_kernel(const int* __restrict__ src, const int* __restrict__ dst,
                    int* __restrict__ cursor, int* __restrict__ csr_src, int E) {
    int e = blockIdx.x * 256 + threadIdx.x;
    if (e < E) {
        int pos = atomicAdd(&cursor[dst[e]], 1);
        csr_src[pos] = src[e];
    }
}

// ---------------------------------------------------------------------------
// fused: mean-aggregate (CSR gather, f64) + hout = agg@Wa + b + h@Wr
// [+BN(eval)+ReLU], all f64.
template<int K, bool HAS_BN, typename TIN>
__global__ __launch_bounds__(128)
void transform_fused(const TIN* __restrict__ h_in,
                     const int* __restrict__ row_start, const int* __restrict__ csr_src,
                     const float* __restrict__ Wa, const float* __restrict__ Wr,
                     const float* __restrict__ b,
                     const float* __restrict__ gamma, const float* __restrict__ beta,
                     const float* __restrict__ mean, const float* __restrict__ var,
                     double* __restrict__ h_out) {
    constexpr int NPB = 8;
    constexpr int KT = 32;
    __shared__ double s_agg[NPB][K];
    __shared__ double s_h[NPB][K];
    __shared__ float s_wa[KT][HID];
    __shared__ float s_wr[KT][HID];
    const int t = threadIdx.x;
    const int n0 = blockIdx.x * NPB;

    for (int p = 0; p < NPB; ++p) {
        int n = n0 + p;
        int r0 = row_start[n], r1 = row_start[n + 1];
        double acc = 0.0;
        if (t < K) {
            for (int i = r0; i < r1; ++i) {
                int s = csr_src[i];
                acc += (double)h_in[(size_t)s * K + t];
            }
            int deg = r1 - r0;
            s_agg[p][t] = acc / (double)(deg > 1 ? deg : 1);
            s_h[p][t] = (double)h_in[(size_t)n * K + t];
        }
    }

    double acc2[NPB];
#pragma unroll
    for (int p = 0; p < NPB; p++) acc2[p] = (double)b[t];

    for (int kt = 0; kt < K; kt += KT) {
        __syncthreads();
        for (int idx = t; idx < KT * HID; idx += 128) {
            int r = idx >> 7, c = idx & 127;
            int k = kt + r;
            s_wa[r][c] = (k < K) ? Wa[(size_t)k * HID + c] : 0.0f;
            s_wr[r][c] = (k < K) ? Wr[(size_t)k * HID + c] : 0.0f;
        }
        __syncthreads();
        int kmax = (K - kt < KT) ? (K - kt) : KT;
        for (int r = 0; r < kmax; ++r) {
            double wa = (double)s_wa[r][t], wr = (double)s_wr[r][t];
#pragma unroll
            for (int p = 0; p < NPB; p++)
                acc2[p] += s_agg[p][kt + r] * wa + s_h[p][kt + r] * wr;
        }
    }

    double scale = 1.0, shift = 0.0;
    if (HAS_BN) {
        scale = (double)gamma[t] / sqrt((double)var[t] + 1e-5);
        shift = (double)beta[t] - (double)mean[t] * scale;
    }
#pragma unroll
    for (int p = 0; p < NPB; p++) {
        double v = acc2[p];
        if (HAS_BN) {
            v = v * scale + shift;
            v = v > 0.0 ? v : 0.0;
        }
        h_out[(size_t)(n0 + p) * HID + t] = v;
    }
}

// ---------------------------------------------------------------------------
// residual VQ. Internals f64, but d2 is assembled IN FP32 with the reference's
// exact association: d2 = fl32( fl32(rr32 - 2*rc32) + cc32 ).  This reproduces
// the reference's fp32 quantization of d2 (ulp(~68) = 7.6e-6), which collapses
// near-ties to equality -> argmin picks the FIRST index, as np/jax do.
__global__ __launch_bounds__(128)
void rvq_kernel(const double* __restrict__ h, const float* __restrict__ cb,
                float* __restrict__ ids_out, int id_col0,
                double* __restrict__ loss_part) {
    constexpr int NODES = 16;
    __shared__ float s_cb[3 * 16 * HID];
    __shared__ float s_cc32[3][16];
    __shared__ double s_res[HID];
    __shared__ double s_part[128];
    __shared__ double s_rrp[16];
    __shared__ double s_rr;
    __shared__ float s_d2[16];
    __shared__ int s_idx;
    __shared__ double s_ws[2];
    const int t = threadIdx.x;

    for (int idx = t; idx < 3 * 16 * HID; idx += 128) s_cb[idx] = cb[idx];
    __syncthreads();
    if (t < 48) {
        const float* c = &s_cb[t * HID];
        double s = 0.0;
        for (int j = 0; j < HID; j++) { double cj = (double)c[j]; s += cj * cj; }
        s_cc32[t / 16][t % 16] = (float)s;
    }
    __syncthreads();

    double block_loss = 0.0;
    const int n0 = blockIdx.x * NODES;
    for (int ni = 0; ni < NODES; ++ni) {
        int n = n0 + ni;
        s_res[t] = h[(size_t)n * HID + t];
        __syncthreads();
        for (int g = 0; g < 3; ++g) {
            // ---- rr = ||res||^2 (f64 reduce) ----
            s_part[t] = s_res[t] * s_res[t];
            __syncthreads();
            if (t < 16) {
                double s = 0.0;
#pragma unroll
                for (int p2 = 0; p2 < 8; p2++) s += s_part[t * 8 + p2];
                s_rrp[t] = s;
            }
            __syncthreads();
            if (t == 0) {
                double s = 0.0;
#pragma unroll
                for (int i = 0; i < 16; i++) s += s_rrp[i];
                s_rr = s;
            }
            __syncthreads();
            float rr32 = (float)s_rr;
            // ---- dots res . c_k (f64 partials) ----
            int k = t >> 3, p = t & 7;
            const float* c = &s_cb[(g * 16 + k) * HID];
            double s = 0.0;
#pragma unroll
            for (int j = 0; j < 16; ++j)
                s += s_res[p * 16 + j] * (double)c[p * 16 + j];
            s_part[t] = s;
            __syncthreads();
            if (t < 16) {
                double dot = 0.0;
#pragma unroll
                for (int p2 = 0; p2 < 8; p2++) dot += s_part[t * 8 + p2];
                float rc32 = (float)dot;
                float t1 = rr32 - 2.0f * rc32;   // fp32 round
                s_d2[t] = t1 + s_cc32[g][t];     // fp32 round -> quantized d2
            }
            __syncthreads();
            if (t == 0) {
                float best = s_d2[0];
                int bi = 0;
#pragma unroll
                for (int k2 = 1; k2 < 16; k2++)
                    if (s_d2[k2] < best) { best = s_d2[k2]; bi = k2; }
                s_idx = bi;
                ids_out[(size_t)n * 9 + id_col0 + g] = (float)bi;
            }
            __syncthreads();
            int bi = s_idx;
            s_res[t] -= (double)s_cb[(g * 16 + bi) * HID + t];
            __syncthreads();
        }
        double r = s_res[t];
        block_loss += r * r;
    }

    double v = block_loss;
#pragma unroll
    for (int off = 32; off; off >>= 1) v += __shfl_down(v, off, 64);
    if ((t & 63) == 0) s_ws[t >> 6] = v;
    __syncthreads();
    if (t == 0) loss_part[blockIdx.x] = s_ws[0] + s_ws[1];
}

// ---------------------------------------------------------------------------
__global__ __launch_bounds__(128)
void linear_kernel(const double* __restrict__ h, const float* __restrict__ W,
                   const float* __restrict__ b, float* __restrict__ out, int N) {
    constexpr int NODES = 32;
    __shared__ float s_w[HID * OUT_C];
    __shared__ float s_b[OUT_C];
    __shared__ double s_h[HID];
    const int t = threadIdx.x;
    for (int idx = t; idx < HID * OUT_C; idx += 128) s_w[idx] = W[idx];
    if (t < OUT_C) s_b[t] = b[t];
    __syncthreads();
    const int n0 = blockIdx.x * NODES;
    for (int ni = 0; ni < NODES; ++ni) {
        int n = n0 + ni;
        if (n >= N) break;
        s_h[t] = h[(size_t)n * HID + t];
        __syncthreads();
        if (t < OUT_C) {
            double acc = (double)s_b[t];
            for (int k = 0; k < HID; k++)
                acc += s_h[k] * (double)s_w[k * OUT_C + t];
            out[(size_t)n * OUT_C + t] = (float)acc;
        }
        __syncthreads();
    }
}

// ---------------------------------------------------------------------------
__global__ __launch_bounds__(256)
void finalize_kernel(const double* __restrict__ loss_part, int M,
                     float* __restrict__ out_loss) {
    __shared__ double s[256];
    const int t = threadIdx.x;
    double v = 0.0;
    for (int i = t; i < M; i += 256) v += loss_part[i];
    s[t] = v;
    __syncthreads();
    for (int off = 128; off; off >>= 1) {
        if (t < off) s[t] += s[t + off];
        __syncthreads();
    }
    if (t == 0) out_loss[0] = (float)(s[0] / ((double)NN * (double)HID));
}

// ---------------------------------------------------------------------------
extern "C" void kernel_launch(void* const* d_in, const int* in_sizes, int n_in,
                              void* d_out, int out_size, void* d_ws, size_t ws_size,
                              hipStream_t stream) {
    const float* x    = (const float*)d_in[0];
    const int*   src  = (const int*)d_in[1];
    const int*   dst  = (const int*)d_in[2];
    const float* W0a = (const float*)d_in[3];
    const float* W0r = (const float*)d_in[4];
    const float* b0  = (const float*)d_in[5];
    const float* W1a = (const float*)d_in[6];
    const float* W1r = (const float*)d_in[7];
    const float* b1  = (const float*)d_in[8];
    const float* W2a = (const float*)d_in[9];
    const float* W2r = (const float*)d_in[10];
    const float* b2  = (const float*)d_in[11];
    const float* bn_gamma = (const float*)d_in[12];
    const float* bn_beta  = (const float*)d_in[13];
    const float* bn_mean  = (const float*)d_in[14];
    const float* bn_var   = (const float*)d_in[15];
    const float* cb    = (const float*)d_in[16];
    const float* lin_W = (const float*)d_in[17];
    const float* lin_b = (const float*)d_in[18];

    const int E = in_sizes[1];

    float* out      = (float*)d_out;                    // [N*40]
    float* out_loss = out + (size_t)NN * OUT_C;         // [1]
    float* out_ids  = out_loss + 1;                     // [N*9] as float

    char* base = (char*)d_ws;
    int* deg_i     = (int*)base;                        // N
    int* row_start = deg_i + NN;                        // N+1
    int* cursor    = row_start + NN + 1;                // N
    int* csr_src   = cursor + NN;                       // E
    size_t int_bytes = ((size_t)(3 * NN + 1 + E) * 4 + 255) & ~(size_t)255;
    double* loss_part = (double*)(base + int_bytes);    // 3*3125
    double* h1 = loss_part + 3 * 3125 + 7;              // N*128 f64
    double* h2 = h1 + (size_t)NN * HID;                 // N*128 f64

    const int cb_layer = 3 * 16 * HID;
    const int NB_RVQ = NN / 16;  // 3125

    hipMemsetAsync(deg_i, 0, NN * sizeof(int), stream);
    hist_kernel<<<(E + 255) / 256, 256, 0, stream>>>(dst, deg_i, E);
    scan_kernel<<<1, 1024, 0, stream>>>(deg_i, row_start, cursor, NN);
    scatter_kernel<<<(E + 255) / 256, 256, 0, stream>>>(src, dst, cursor, csr_src, E);

    transform_fused<IN_C, true, float><<<NN / 8, 128, 0, stream>>>(
        x, row_start, csr_src, W0a, W0r, b0, bn_gamma, bn_beta, bn_mean, bn_var, h1);
    rvq_kernel<<<NB_RVQ, 128, 0, stream>>>(h1, cb + 0 * cb_layer, out_ids, 0, loss_part);

    transform_fused<HID, true, double><<<NN / 8, 128, 0, stream>>>(
        h1, row_start, csr_src, W1a, W1r, b1,
        bn_gamma + HID, bn_beta + HID, bn_mean + HID, bn_var + HID, h2);
    rvq_kernel<<<NB_RVQ, 128, 0, stream>>>(h2, cb + 1 * cb_layer, out_ids, 3, loss_part + NB_RVQ);

    transform_fused<HID, false, double><<<NN / 8, 128, 0, stream>>>(
        h2, row_start, csr_src, W2a, W2r, b2, nullptr, nullptr, nullptr, nullptr, h1);
    rvq_kernel<<<NB_RVQ, 128, 0, stream>>>(h1, cb + 2 * cb_layer, out_ids, 6, loss_part + 2 * NB_RVQ);

    linear_kernel<<<(NN + 31) / 32, 128, 0, stream>>>(h1, lin_W, lin_b, out, NN);
    finalize_kernel<<<1, 256, 0, stream>>>(loss_part, 3 * NB_RVQ, out_loss);
}

// Round 5
// 1122.216 us; speedup vs baseline: 12.0591x; 12.0591x over previous
//
#include <hip/hip_runtime.h>

#define NN 50000
#define HID 128
#define IN_C 100
#define OUT_C 40

// ---------------------------------------------------------------------------
__global__ __launch_bounds__(256)
void hist_kernel(const int* __restrict__ dst, int* __restrict__ deg, int E) {
    int e = blockIdx.x * 256 + threadIdx.x;
    if (e < E) atomicAdd(&deg[dst[e]], 1);
}

// ---------------------------------------------------------------------------
__global__ __launch_bounds__(1024)
void scan_kernel(const int* __restrict__ deg, int* __restrict__ row_start,
                 int* __restrict__ cursor, int N) {
    __shared__ int s[1024];
    const int t = threadIdx.x;
    int running = 0;
    for (int c0 = 0; c0 < N; c0 += 1024) {
        int i = c0 + t;
        int v = (i < N) ? deg[i] : 0;
        s[t] = v;
        __syncthreads();
        for (int off = 1; off < 1024; off <<= 1) {
            int x = (t >= off) ? s[t - off] : 0;
            __syncthreads();
            s[t] += x;
            __syncthreads();
        }
        if (i < N) {
            int ex = running + s[t] - v;
            row_start[i] = ex;
            cursor[i] = ex;
        }
        running += s[1023];
        __syncthreads();
    }
    if (t == 0) row_start[N] = running;
}

// ---------------------------------------------------------------------------
__global__ __launch_bounds__(256)
void scatter_kernel(const int* __restrict__ src, const int* __restrict__ dst,
                    int* __restrict__ cursor, int* __restrict__ csr_src, int E) {
    int e = blockIdx.x * 256 + threadIdx.x;
    if (e < E) {
        int pos = atomicAdd(&cursor[dst[e]], 1);
        csr_src[pos] = src[e];
    }
}

// ---------------------------------------------------------------------------
// fused mean-aggregate + transform, v2: 4 waves/block, wave-per-node gather,
// then column-parallel GEMM (f64). LDS 8KB, VGPR-capped.
template<int K, bool HAS_BN, typename TIN>
__global__ __launch_bounds__(256, 4)
void transform_fused(const TIN* __restrict__ h_in,
                     const int* __restrict__ row_start, const int* __restrict__ csr_src,
                     const float* __restrict__ Wa, const float* __restrict__ Wr,
                     const float* __restrict__ b,
                     const float* __restrict__ gamma, const float* __restrict__ beta,
                     const float* __restrict__ mean, const float* __restrict__ var,
                     double* __restrict__ h_out) {
    __shared__ double s_agg[4][K];
    __shared__ double s_h[4][K];
    const int t = threadIdx.x;
    const int w = t >> 6;          // wave 0..3
    const int lane = t & 63;
    const int n0 = blockIdx.x * 4;

    // ---- phase A: wave w gathers node n0+w (2 features per lane) ----
    {
        const int n = n0 + w;
        const int r0 = row_start[n], r1 = row_start[n + 1];
        const int f0 = lane, f1 = lane + 64;
        double a0 = 0.0, a1 = 0.0, c0 = 0.0, c1 = 0.0;
        int i = r0;
        for (; i + 1 < r1; i += 2) {
            const int s0 = csr_src[i], s1 = csr_src[i + 1];
            const TIN* p0 = h_in + (size_t)s0 * K;
            const TIN* p1 = h_in + (size_t)s1 * K;
            if (f0 < K) { a0 += (double)p0[f0]; c0 += (double)p1[f0]; }
            if (f1 < K) { a1 += (double)p0[f1]; c1 += (double)p1[f1]; }
        }
        if (i < r1) {
            const int s0 = csr_src[i];
            const TIN* p0 = h_in + (size_t)s0 * K;
            if (f0 < K) a0 += (double)p0[f0];
            if (f1 < K) a1 += (double)p0[f1];
        }
        const int deg = r1 - r0;
        const double dd = (double)(deg > 1 ? deg : 1);
        const TIN* pr = h_in + (size_t)n * K;
        if (f0 < K) { s_agg[w][f0] = (a0 + c0) / dd; s_h[w][f0] = (double)pr[f0]; }
        if (f1 < K) { s_agg[w][f1] = (a1 + c1) / dd; s_h[w][f1] = (double)pr[f1]; }
    }
    __syncthreads();

    // ---- phase B: GEMM. thread = (col, node-pair). pr2 uniform per wave. ----
    const int col = t & 127;
    const int pr2 = t >> 7;        // 0 or 1; handles nodes pr2 and pr2+2
    double accA = (double)b[col];
    double accB = accA;
#pragma unroll 4
    for (int k = 0; k < K; ++k) {
        const double wa = (double)Wa[(size_t)k * HID + col];
        const double wr = (double)Wr[(size_t)k * HID + col];
        accA += s_agg[pr2][k] * wa + s_h[pr2][k] * wr;
        accB += s_agg[pr2 + 2][k] * wa + s_h[pr2 + 2][k] * wr;
    }

    // ---- phase C: BN(eval) + ReLU ----
    double scale = 1.0, shift = 0.0;
    if (HAS_BN) {
        scale = (double)gamma[col] / sqrt((double)var[col] + 1e-5);
        shift = (double)beta[col] - (double)mean[col] * scale;
    }
    double vA = accA, vB = accB;
    if (HAS_BN) {
        vA = vA * scale + shift; vA = vA > 0.0 ? vA : 0.0;
        vB = vB * scale + shift; vB = vB > 0.0 ? vB : 0.0;
    }
    h_out[(size_t)(n0 + pr2) * HID + col] = vA;
    h_out[(size_t)(n0 + pr2 + 2) * HID + col] = vB;
}

// ---------------------------------------------------------------------------
// residual VQ v2: 4 waves/block, wave-per-node. Numerics recipe identical to
// round 4: f64 rr/dot/cc, d2 = fl32(fl32(rr32 - 2*rc32) + cc32), first-min.
__global__ __launch_bounds__(256)
void rvq_kernel(const double* __restrict__ h, const float* __restrict__ cb,
                float* __restrict__ ids_out, int id_col0,
                double* __restrict__ loss_part) {
    constexpr int NPB = 16;                 // nodes per block
    __shared__ float s_cb[3 * 16 * 129];    // padded stride 129
    __shared__ float s_cc32[3][16];
    __shared__ double s_res[4][128];
    __shared__ double s_ws[4];
    const int t = threadIdx.x;
    const int w = t >> 6, lane = t & 63;

    for (int idx = t; idx < 3 * 16 * 128; idx += 256) {
        int kk = idx >> 7, j = idx & 127;
        s_cb[kk * 129 + j] = cb[idx];
    }
    __syncthreads();
    if (t < 48) {
        const float* c = &s_cb[t * 129];
        double s = 0.0;
        for (int j = 0; j < 128; j++) { double cj = (double)c[j]; s += cj * cj; }
        s_cc32[t >> 4][t & 15] = (float)s;
    }
    __syncthreads();

    double wave_loss = 0.0;
    const int n0 = blockIdx.x * NPB;
    const int k = lane & 15, q = lane >> 4;

    for (int it = 0; it < NPB / 4; ++it) {
        const int n = n0 + it * 4 + w;
        s_res[w][lane] = h[(size_t)n * 128 + lane];
        s_res[w][lane + 64] = h[(size_t)n * 128 + lane + 64];
        __syncthreads();

        for (int g = 0; g < 3; ++g) {
            // rr = ||res||^2 (f64 butterfly)
            double r0 = s_res[w][lane], r1 = s_res[w][lane + 64];
            double pr = r0 * r0 + r1 * r1;
            pr += __shfl_xor(pr, 1, 64);
            pr += __shfl_xor(pr, 2, 64);
            pr += __shfl_xor(pr, 4, 64);
            pr += __shfl_xor(pr, 8, 64);
            pr += __shfl_xor(pr, 16, 64);
            pr += __shfl_xor(pr, 32, 64);
            const float rr32 = (float)pr;

            // dot(res, c_k): lane (k,q) does 32 features with q-rotation
            const float* c = &s_cb[(g * 16 + k) * 129];
            double dot = 0.0;
#pragma unroll
            for (int j2 = 0; j2 < 32; ++j2) {
                int j = q * 32 + ((j2 + q * 8) & 31);
                dot += s_res[w][j] * (double)c[j];
            }
            dot += __shfl_xor(dot, 16, 64);
            dot += __shfl_xor(dot, 32, 64);   // every lane: full dot for its k

            const float rc32 = (float)dot;
            const float t1 = rr32 - 2.0f * rc32;     // fp32 round
            const float d2 = t1 + s_cc32[g][k];      // fp32 round

            // first-min argmin over 16 codes (butterfly, tie -> smaller idx)
            float bv = d2; int bk = k;
            {
                float ov; int ok;
                ov = __shfl_xor(bv, 1, 64); ok = __shfl_xor(bk, 1, 64);
                if (ov < bv || (ov == bv && ok < bk)) { bv = ov; bk = ok; }
                ov = __shfl_xor(bv, 2, 64); ok = __shfl_xor(bk, 2, 64);
                if (ov < bv || (ov == bv && ok < bk)) { bv = ov; bk = ok; }
                ov = __shfl_xor(bv, 4, 64); ok = __shfl_xor(bk, 4, 64);
                if (ov < bv || (ov == bv && ok < bk)) { bv = ov; bk = ok; }
                ov = __shfl_xor(bv, 8, 64); ok = __shfl_xor(bk, 8, 64);
                if (ov < bv || (ov == bv && ok < bk)) { bv = ov; bk = ok; }
            }
            if (lane == 0)
                ids_out[(size_t)n * 9 + id_col0 + g] = (float)bk;

            __syncthreads();
            s_res[w][lane]      -= (double)s_cb[(g * 16 + bk) * 129 + lane];
            s_res[w][lane + 64] -= (double)s_cb[(g * 16 + bk) * 129 + lane + 64];
            __syncthreads();
        }
        double r0 = s_res[w][lane], r1 = s_res[w][lane + 64];
        wave_loss += r0 * r0 + r1 * r1;
        __syncthreads();
    }

    wave_loss += __shfl_xor(wave_loss, 1, 64);
    wave_loss += __shfl_xor(wave_loss, 2, 64);
    wave_loss += __shfl_xor(wave_loss, 4, 64);
    wave_loss += __shfl_xor(wave_loss, 8, 64);
    wave_loss += __shfl_xor(wave_loss, 16, 64);
    wave_loss += __shfl_xor(wave_loss, 32, 64);
    if (lane == 0) s_ws[w] = wave_loss;
    __syncthreads();
    if (t == 0) loss_part[blockIdx.x] = s_ws[0] + s_ws[1] + s_ws[2] + s_ws[3];
}

// ---------------------------------------------------------------------------
__global__ __launch_bounds__(128)
void linear_kernel(const double* __restrict__ h, const float* __restrict__ W,
                   const float* __restrict__ b, float* __restrict__ out, int N) {
    constexpr int NODES = 32;
    __shared__ float s_w[HID * OUT_C];
    __shared__ float s_b[OUT_C];
    __shared__ double s_h[HID];
    const int t = threadIdx.x;
    for (int idx = t; idx < HID * OUT_C; idx += 128) s_w[idx] = W[idx];
    if (t < OUT_C) s_b[t] = b[t];
    __syncthreads();
    const int n0 = blockIdx.x * NODES;
    for (int ni = 0; ni < NODES; ++ni) {
        int n = n0 + ni;
        if (n >= N) break;
        s_h[t] = h[(size_t)n * HID + t];
        __syncthreads();
        if (t < OUT_C) {
            double acc = (double)s_b[t];
            for (int kk = 0; kk < HID; kk++)
                acc += s_h[kk] * (double)s_w[kk * OUT_C + t];
            out[(size_t)n * OUT_C + t] = (float)acc;
        }
        __syncthreads();
    }
}

// ---------------------------------------------------------------------------
__global__ __launch_bounds__(256)
void finalize_kernel(const double* __restrict__ loss_part, int M,
                     float* __restrict__ out_loss) {
    __shared__ double s[256];
    const int t = threadIdx.x;
    double v = 0.0;
    for (int i = t; i < M; i += 256) v += loss_part[i];
    s[t] = v;
    __syncthreads();
    for (int off = 128; off; off >>= 1) {
        if (t < off) s[t] += s[t + off];
        __syncthreads();
    }
    if (t == 0) out_loss[0] = (float)(s[0] / ((double)NN * (double)HID));
}

// ---------------------------------------------------------------------------
extern "C" void kernel_launch(void* const* d_in, const int* in_sizes, int n_in,
                              void* d_out, int out_size, void* d_ws, size_t ws_size,
                              hipStream_t stream) {
    const float* x    = (const float*)d_in[0];
    const int*   src  = (const int*)d_in[1];
    const int*   dst  = (const int*)d_in[2];
    const float* W0a = (const float*)d_in[3];
    const float* W0r = (const float*)d_in[4];
    const float* b0  = (const float*)d_in[5];
    const float* W1a = (const float*)d_in[6];
    const float* W1r = (const float*)d_in[7];
    const float* b1  = (const float*)d_in[8];
    const float* W2a = (const float*)d_in[9];
    const float* W2r = (const float*)d_in[10];
    const float* b2  = (const float*)d_in[11];
    const float* bn_gamma = (const float*)d_in[12];
    const float* bn_beta  = (const float*)d_in[13];
    const float* bn_mean  = (const float*)d_in[14];
    const float* bn_var   = (const float*)d_in[15];
    const float* cb    = (const float*)d_in[16];
    const float* lin_W = (const float*)d_in[17];
    const float* lin_b = (const float*)d_in[18];

    const int E = in_sizes[1];

    float* out      = (float*)d_out;                    // [N*40]
    float* out_loss = out + (size_t)NN * OUT_C;         // [1]
    float* out_ids  = out_loss + 1;                     // [N*9] as float

    char* base = (char*)d_ws;
    int* deg_i     = (int*)base;                        // N
    int* row_start = deg_i + NN;                        // N+1
    int* cursor    = row_start + NN + 1;                // N
    int* csr_src   = cursor + NN;                       // E
    size_t int_bytes = ((size_t)(3 * NN + 1 + E) * 4 + 255) & ~(size_t)255;
    double* loss_part = (double*)(base + int_bytes);    // 3*3125
    double* h1 = loss_part + 3 * 3125 + 7;              // N*128 f64
    double* h2 = h1 + (size_t)NN * HID;                 // N*128 f64

    const int cb_layer = 3 * 16 * HID;
    const int NB_RVQ = NN / 16;  // 3125

    hipMemsetAsync(deg_i, 0, NN * sizeof(int), stream);
    hist_kernel<<<(E + 255) / 256, 256, 0, stream>>>(dst, deg_i, E);
    scan_kernel<<<1, 1024, 0, stream>>>(deg_i, row_start, cursor, NN);
    scatter_kernel<<<(E + 255) / 256, 256, 0, stream>>>(src, dst, cursor, csr_src, E);

    transform_fused<IN_C, true, float><<<NN / 4, 256, 0, stream>>>(
        x, row_start, csr_src, W0a, W0r, b0, bn_gamma, bn_beta, bn_mean, bn_var, h1);
    rvq_kernel<<<NB_RVQ, 256, 0, stream>>>(h1, cb + 0 * cb_layer, out_ids, 0, loss_part);

    transform_fused<HID, true, double><<<NN / 4, 256, 0, stream>>>(
        h1, row_start, csr_src, W1a, W1r, b1,
        bn_gamma + HID, bn_beta + HID, bn_mean + HID, bn_var + HID, h2);
    rvq_kernel<<<NB_RVQ, 256, 0, stream>>>(h2, cb + 1 * cb_layer, out_ids, 3, loss_part + NB_RVQ);

    transform_fused<HID, false, double><<<NN / 4, 256, 0, stream>>>(
        h2, row_start, csr_src, W2a, W2r, b2, nullptr, nullptr, nullptr, nullptr, h1);
    rvq_kernel<<<NB_RVQ, 256, 0, stream>>>(h1, cb + 2 * cb_layer, out_ids, 6, loss_part + 2 * NB_RVQ);

    linear_kernel<<<(NN + 31) / 32, 128, 0, stream>>>(h1, lin_W, lin_b, out, NN);
    finalize_kernel<<<1, 256, 0, stream>>>(loss_part, 3 * NB_RVQ, out_loss);
}

// Round 6
// 1028.939 us; speedup vs baseline: 13.1523x; 1.0907x over previous
//
#include <hip/hip_runtime.h>

#define NN 50000
#define HID 128
#define IN_C 100
#define OUT_C 40

// ---------------------------------------------------------------------------
__global__ __launch_bounds__(256)
void hist_kernel(const int* __restrict__ dst, int* __restrict__ deg, int E) {
    int e = blockIdx.x * 256 + threadIdx.x;
    if (e < E) atomicAdd(&deg[dst[e]], 1);
}

// ---------------------------------------------------------------------------
// chunked exclusive scan (50000 elements, 256-wide chunks)
__global__ __launch_bounds__(256)
void chunk_sum_kernel(const int* __restrict__ deg, int* __restrict__ chunk_sums, int N) {
    __shared__ int s[256];
    const int t = threadIdx.x;
    const int i = blockIdx.x * 256 + t;
    s[t] = (i < N) ? deg[i] : 0;
    __syncthreads();
    for (int o = 128; o; o >>= 1) { if (t < o) s[t] += s[t + o]; __syncthreads(); }
    if (t == 0) chunk_sums[blockIdx.x] = s[0];
}

__global__ __launch_bounds__(256)
void chunk_scan_kernel(int* __restrict__ chunk_sums, int M) {
    __shared__ int s[256];
    const int t = threadIdx.x;
    int v = (t < M) ? chunk_sums[t] : 0;
    s[t] = v;
    __syncthreads();
    for (int o = 1; o < 256; o <<= 1) {
        int x = (t >= o) ? s[t - o] : 0;
        __syncthreads();
        s[t] += x;
        __syncthreads();
    }
    if (t < M) chunk_sums[t] = s[t] - v;   // exclusive
}

__global__ __launch_bounds__(256)
void chunk_apply_kernel(const int* __restrict__ deg, const int* __restrict__ chunk_sums,
                        int* __restrict__ row_start, int* __restrict__ cursor, int N) {
    __shared__ int s[256];
    const int t = threadIdx.x;
    const int i = blockIdx.x * 256 + t;
    int v = (i < N) ? deg[i] : 0;
    s[t] = v;
    __syncthreads();
    for (int o = 1; o < 256; o <<= 1) {
        int x = (t >= o) ? s[t - o] : 0;
        __syncthreads();
        s[t] += x;
        __syncthreads();
    }
    if (i < N) {
        int ex = chunk_sums[blockIdx.x] + s[t] - v;
        row_start[i] = ex;
        cursor[i] = ex;
        if (i == N - 1) row_start[N] = ex + v;
    }
}

// ---------------------------------------------------------------------------
__global__ __launch_bounds__(256)
void scatter_kernel(const int* __restrict__ src, const int* __restrict__ dst,
                    int* __restrict__ cursor, int* __restrict__ csr_src, int E) {
    int e = blockIdx.x * 256 + threadIdx.x;
    if (e < E) {
        int pos = atomicAdd(&cursor[dst[e]], 1);
        csr_src[pos] = src[e];
    }
}

// ---------------------------------------------------------------------------
// fused layer: mean-aggregate (CSR gather, f64) + GEMM (f64) + BN/ReLU + RVQ.
// 512 threads = 8 waves, 8 nodes/block (wave-per-node gather + wave-per-node rvq).
// Numerics recipe (DO NOT CHANGE): f64 h end-to-end; d2 assembled in fp32 as
// fl32(fl32(rr32 - 2*rc32) + cc32); argmin = first-min.
template<int K, bool HAS_BN, typename TIN>
__global__ __launch_bounds__(512, 6)
void layer_fused(const TIN* __restrict__ h_in,
                 const int* __restrict__ row_start, const int* __restrict__ csr_src,
                 const float* __restrict__ Wa, const float* __restrict__ Wr,
                 const float* __restrict__ b,
                 const float* __restrict__ gamma, const float* __restrict__ beta,
                 const float* __restrict__ mean, const float* __restrict__ var,
                 const float* __restrict__ cb,       // [3*16*128] this layer
                 double* __restrict__ h_out,
                 float* __restrict__ ids_out, int id_col0,
                 double* __restrict__ loss_part) {
    __shared__ double s_agg[8][HID];   // phase A: agg; phase C/D: h rows (rvq res)
    __shared__ double s_h[8][HID];     // root features
    __shared__ float s_cb[3 * 16 * 129];
    __shared__ float s_cc32[3][16];
    __shared__ double s_ws[8];
    const int t = threadIdx.x;
    const int w = t >> 6, lane = t & 63;
    const int n0 = blockIdx.x * 8;

    // ---- phase A: wave w gathers node n0+w; lane covers features 2*lane,2*lane+1
    {
        const int n = n0 + w;
        const int r0 = row_start[n], r1 = row_start[n + 1];
        const int f0 = 2 * lane;
        if (f0 < K) {
            double a0 = 0.0, a1 = 0.0, c0 = 0.0, c1 = 0.0;
            int i = r0;
            for (; i + 1 < r1; i += 2) {
                const TIN* p0 = h_in + (size_t)csr_src[i] * K + f0;
                const TIN* p1 = h_in + (size_t)csr_src[i + 1] * K + f0;
                a0 += (double)p0[0]; a1 += (double)p0[1];
                c0 += (double)p1[0]; c1 += (double)p1[1];
            }
            if (i < r1) {
                const TIN* p0 = h_in + (size_t)csr_src[i] * K + f0;
                a0 += (double)p0[0]; a1 += (double)p0[1];
            }
            const int deg = r1 - r0;
            const double dd = (double)(deg > 1 ? deg : 1);
            const TIN* pr = h_in + (size_t)n * K + f0;
            s_agg[w][f0]     = (a0 + c0) / dd;
            s_agg[w][f0 + 1] = (a1 + c1) / dd;
            s_h[w][f0]     = (double)pr[0];
            s_h[w][f0 + 1] = (double)pr[1];
        }
    }
    __syncthreads();

    // ---- codebook -> LDS (overlaps with GEMM's weight streaming) ----
    for (int idx = t; idx < 3 * 16 * 128; idx += 512)
        s_cb[(idx >> 7) * 129 + (idx & 127)] = cb[idx];

    // ---- phase B: GEMM. thread = (col, p4); nodes p4 and p4+4 ----
    const int col = t & 127;
    const int p4 = t >> 7;      // 0..3
    double accA = (double)b[col];
    double accB = accA;
#pragma unroll 4
    for (int k = 0; k < K; ++k) {
        const double wa = (double)Wa[(size_t)k * HID + col];
        const double wr = (double)Wr[(size_t)k * HID + col];
        accA += s_agg[p4][k] * wa + s_h[p4][k] * wr;
        accB += s_agg[p4 + 4][k] * wa + s_h[p4 + 4][k] * wr;
    }
    __syncthreads();   // GEMM done reading s_agg/s_h; s_cb resident

    // ---- phase C: BN(eval)+ReLU, global write, stash rows for RVQ ----
    {
        double scale = 1.0, shift = 0.0;
        if (HAS_BN) {
            scale = (double)gamma[col] / sqrt((double)var[col] + 1e-5);
            shift = (double)beta[col] - (double)mean[col] * scale;
        }
        double vA = accA, vB = accB;
        if (HAS_BN) {
            vA = vA * scale + shift; vA = vA > 0.0 ? vA : 0.0;
            vB = vB * scale + shift; vB = vB > 0.0 ? vB : 0.0;
        }
        h_out[(size_t)(n0 + p4) * HID + col] = vA;
        h_out[(size_t)(n0 + p4 + 4) * HID + col] = vB;
        s_agg[p4][col] = vA;
        s_agg[p4 + 4][col] = vB;
    }
    if (t < 48) {
        const float* c = &s_cb[t * 129];
        double s = 0.0;
        for (int j = 0; j < 128; j++) { double cj = (double)c[j]; s += cj * cj; }
        s_cc32[t >> 4][t & 15] = (float)s;
    }
    __syncthreads();

    // ---- phase D: RVQ, wave w on its node's row (wave-lockstep, no barriers)
    {
        double* res = &s_agg[w][0];
        const int n = n0 + w;
        const int k = lane & 15, q = lane >> 4;

        for (int g = 0; g < 3; ++g) {
            // rr = ||res||^2 (f64 butterfly)
            double r0 = res[lane], r1 = res[lane + 64];
            double pr = r0 * r0 + r1 * r1;
            pr += __shfl_xor(pr, 1, 64);
            pr += __shfl_xor(pr, 2, 64);
            pr += __shfl_xor(pr, 4, 64);
            pr += __shfl_xor(pr, 8, 64);
            pr += __shfl_xor(pr, 16, 64);
            pr += __shfl_xor(pr, 32, 64);
            const float rr32 = (float)pr;

            // dot(res, c_k): lane (k,q) does quarter q with rotation
            const float* c = &s_cb[(g * 16 + k) * 129];
            double dot = 0.0;
#pragma unroll
            for (int j2 = 0; j2 < 32; ++j2) {
                int j = q * 32 + ((j2 + q * 8) & 31);
                dot += res[j] * (double)c[j];
            }
            dot += __shfl_xor(dot, 16, 64);
            dot += __shfl_xor(dot, 32, 64);

            const float rc32 = (float)dot;
            const float t1 = rr32 - 2.0f * rc32;     // fp32 round
            const float d2 = t1 + s_cc32[g][k];      // fp32 round

            // first-min argmin over 16 codes
            float bv = d2; int bk = k;
            {
                float ov; int ok;
                ov = __shfl_xor(bv, 1, 64); ok = __shfl_xor(bk, 1, 64);
                if (ov < bv || (ov == bv && ok < bk)) { bv = ov; bk = ok; }
                ov = __shfl_xor(bv, 2, 64); ok = __shfl_xor(bk, 2, 64);
                if (ov < bv || (ov == bv && ok < bk)) { bv = ov; bk = ok; }
                ov = __shfl_xor(bv, 4, 64); ok = __shfl_xor(bk, 4, 64);
                if (ov < bv || (ov == bv && ok < bk)) { bv = ov; bk = ok; }
                ov = __shfl_xor(bv, 8, 64); ok = __shfl_xor(bk, 8, 64);
                if (ov < bv || (ov == bv && ok < bk)) { bv = ov; bk = ok; }
            }
            if (lane == 0)
                ids_out[(size_t)n * 9 + id_col0 + g] = (float)bk;

            res[lane]      -= (double)s_cb[(g * 16 + bk) * 129 + lane];
            res[lane + 64] -= (double)s_cb[(g * 16 + bk) * 129 + lane + 64];
        }
        double r0 = res[lane], r1 = res[lane + 64];
        double wl = r0 * r0 + r1 * r1;
        wl += __shfl_xor(wl, 1, 64);
        wl += __shfl_xor(wl, 2, 64);
        wl += __shfl_xor(wl, 4, 64);
        wl += __shfl_xor(wl, 8, 64);
        wl += __shfl_xor(wl, 16, 64);
        wl += __shfl_xor(wl, 32, 64);
        if (lane == 0) s_ws[w] = wl;
    }
    __syncthreads();
    if (t == 0) {
        double s = 0.0;
#pragma unroll
        for (int i = 0; i < 8; i++) s += s_ws[i];
        loss_part[blockIdx.x] = s;
    }
}

// ---------------------------------------------------------------------------
__global__ __launch_bounds__(128)
void linear_kernel(const double* __restrict__ h, const float* __restrict__ W,
                   const float* __restrict__ b, float* __restrict__ out, int N) {
    constexpr int NODES = 32;
    __shared__ float s_w[HID * OUT_C];
    __shared__ float s_b[OUT_C];
    __shared__ double s_h[HID];
    const int t = threadIdx.x;
    for (int idx = t; idx < HID * OUT_C; idx += 128) s_w[idx] = W[idx];
    if (t < OUT_C) s_b[t] = b[t];
    __syncthreads();
    const int n0 = blockIdx.x * NODES;
    for (int ni = 0; ni < NODES; ++ni) {
        int n = n0 + ni;
        if (n >= N) break;
        s_h[t] = h[(size_t)n * HID + t];
        __syncthreads();
        if (t < OUT_C) {
            double acc = (double)s_b[t];
            for (int kk = 0; kk < HID; kk++)
                acc += s_h[kk] * (double)s_w[kk * OUT_C + t];
            out[(size_t)n * OUT_C + t] = (float)acc;
        }
        __syncthreads();
    }
}

// ---------------------------------------------------------------------------
__global__ __launch_bounds__(256)
void finalize_kernel(const double* __restrict__ loss_part, int M,
                     float* __restrict__ out_loss) {
    __shared__ double s[256];
    const int t = threadIdx.x;
    double v = 0.0;
    for (int i = t; i < M; i += 256) v += loss_part[i];
    s[t] = v;
    __syncthreads();
    for (int off = 128; off; off >>= 1) {
        if (t < off) s[t] += s[t + off];
        __syncthreads();
    }
    if (t == 0) out_loss[0] = (float)(s[0] / ((double)NN * (double)HID));
}

// ---------------------------------------------------------------------------
extern "C" void kernel_launch(void* const* d_in, const int* in_sizes, int n_in,
                              void* d_out, int out_size, void* d_ws, size_t ws_size,
                              hipStream_t stream) {
    const float* x    = (const float*)d_in[0];
    const int*   src  = (const int*)d_in[1];
    const int*   dst  = (const int*)d_in[2];
    const float* W0a = (const float*)d_in[3];
    const float* W0r = (const float*)d_in[4];
    const float* b0  = (const float*)d_in[5];
    const float* W1a = (const float*)d_in[6];
    const float* W1r = (const float*)d_in[7];
    const float* b1  = (const float*)d_in[8];
    const float* W2a = (const float*)d_in[9];
    const float* W2r = (const float*)d_in[10];
    const float* b2  = (const float*)d_in[11];
    const float* bn_gamma = (const float*)d_in[12];
    const float* bn_beta  = (const float*)d_in[13];
    const float* bn_mean  = (const float*)d_in[14];
    const float* bn_var   = (const float*)d_in[15];
    const float* cb    = (const float*)d_in[16];
    const float* lin_W = (const float*)d_in[17];
    const float* lin_b = (const float*)d_in[18];

    const int E = in_sizes[1];

    float* out      = (float*)d_out;                    // [N*40]
    float* out_loss = out + (size_t)NN * OUT_C;         // [1]
    float* out_ids  = out_loss + 1;                     // [N*9] as float

    char* base = (char*)d_ws;
    int* deg_i      = (int*)base;                       // N
    int* row_start  = deg_i + NN;                       // N+1
    int* cursor     = row_start + NN + 1;               // N
    int* csr_src    = cursor + NN;                      // E
    int* chunk_sums = csr_src + E;                      // 256
    size_t int_bytes = ((size_t)(3 * NN + 1 + E + 256) * 4 + 255) & ~(size_t)255;
    double* loss_part = (double*)(base + int_bytes);    // 3*6250
    double* h1 = loss_part + 3 * 6250 + 6;              // N*128 f64
    double* h2 = h1 + (size_t)NN * HID;                 // N*128 f64

    const int cb_layer = 3 * 16 * HID;
    const int NB = NN / 8;                              // 6250 blocks
    const int NCHUNK = (NN + 255) / 256;                // 196

    // ---- CSR build ----
    hipMemsetAsync(deg_i, 0, NN * sizeof(int), stream);
    hist_kernel<<<(E + 255) / 256, 256, 0, stream>>>(dst, deg_i, E);
    chunk_sum_kernel<<<NCHUNK, 256, 0, stream>>>(deg_i, chunk_sums, NN);
    chunk_scan_kernel<<<1, 256, 0, stream>>>(chunk_sums, NCHUNK);
    chunk_apply_kernel<<<NCHUNK, 256, 0, stream>>>(deg_i, chunk_sums, row_start, cursor, NN);
    scatter_kernel<<<(E + 255) / 256, 256, 0, stream>>>(src, dst, cursor, csr_src, E);

    // ---- fused layers ----
    layer_fused<IN_C, true, float><<<NB, 512, 0, stream>>>(
        x, row_start, csr_src, W0a, W0r, b0, bn_gamma, bn_beta, bn_mean, bn_var,
        cb + 0 * cb_layer, h1, out_ids, 0, loss_part);

    layer_fused<HID, true, double><<<NB, 512, 0, stream>>>(
        h1, row_start, csr_src, W1a, W1r, b1,
        bn_gamma + HID, bn_beta + HID, bn_mean + HID, bn_var + HID,
        cb + 1 * cb_layer, h2, out_ids, 3, loss_part + NB);

    layer_fused<HID, false, double><<<NB, 512, 0, stream>>>(
        h2, row_start, csr_src, W2a, W2r, b2, nullptr, nullptr, nullptr, nullptr,
        cb + 2 * cb_layer, h1, out_ids, 6, loss_part + 2 * NB);

    // ---- head + loss ----
    linear_kernel<<<(NN + 31) / 32, 128, 0, stream>>>(h1, lin_W, lin_b, out, NN);
    finalize_kernel<<<1, 256, 0, stream>>>(loss_part, 3 * NB, out_loss);
}